// Round 9
// baseline (14964.978 us; speedup 1.0000x reference)
//
#include <hip/hip_runtime.h>
#include <math.h>

#define V 13000
#define D 300
#define M 500
#define B 64
#define NW 5
#define T 128
#define NSUP (B*NW)        // 320
#define NSEQ (NSUP + B)    // 384
#define CT 32              // chains per tile
#define NCT 12             // 384/32
#define MT 16              // m per block
#define KSPL 4             // K splits (one wave each)
#define CHK 20             // k per chunk
#define CKS 10             // chunks per split (4*10*20 = 800)
#define KROW 800           // act row length (k<300: x, k>=300: c)
#define NSTEP (T-1)        // 127
#define ASTR 49            // LDS floats per k-row of A (48 used + 1 pad)
#define BSTR 36            // LDS floats per k-row of B (32 used + 4 pad)
#define APW (CHK*ASTR)     // 980 floats per split
#define BPW (CHK*BSTR)     // 720 floats per split
#define SMSZ (KSPL*(APW+BPW))  // 6800 floats (> red 6144)
#define NCOMP 768          // 2 dir * 12 ct * 32 mt
#define NGATH (2*NSEQ)     // 768

__device__ __forceinline__ float sigmoidf_(float x){ return 1.0f/(1.0f+expf(-x)); }

// actB layout: actB[(d*KROW + k)*NSEQ + rank];  c part at k = 300+m.
// c_final layout: c_final[(d*NSEQ + chain)*M + m]

__global__ void init_kernel(const float* __restrict__ c0L, const float* __restrict__ c0R,
                            float* __restrict__ actB0, float* __restrict__ c_final)
{
    int idx = blockIdx.x*256 + threadIdx.x;      // 2*M*NSEQ
    if (idx >= 2*M*NSEQ) return;
    int d = idx / (M*NSEQ);
    int rem = idx % (M*NSEQ);
    int m = rem / NSEQ;
    int r = rem % NSEQ;
    float v = d ? c0R[m] : c0L[m];
    actB0[((size_t)d*KROW + 300 + m)*NSEQ + r] = v;
    c_final[((size_t)d*NSEQ + r)*M + m] = v;
}

__global__ void sort_kernel(const int* __restrict__ blank_sup, const int* __restrict__ blank_tgt,
                            int* __restrict__ perm, int* __restrict__ lenR, int* __restrict__ tmax)
{
    __shared__ int L0[NSEQ], L1[NSEQ];
    int tid = threadIdx.x;                       // 384 threads
    int blank = (tid < NSUP) ? blank_sup[tid] : blank_tgt[tid - NSUP];
    int l0 = blank, l1 = (T-1) - blank;
    L0[tid] = l0; L1[tid] = l1;
    __syncthreads();
    int r0 = 0, r1 = 0;
    for (int j = 0; j < NSEQ; ++j) {
        int c = L0[j]; r0 += (c > l0) || (c == l0 && j < tid);
        int d = L1[j]; r1 += (d > l1) || (d == l1 && j < tid);
    }
    perm[r0] = tid;        lenR[r0] = l0;
    perm[NSEQ + r1] = tid; lenR[NSEQ + r1] = l1;
    __syncthreads();
    if (tid < 2*NCT) {
        int dir = tid / NCT, t = tid % NCT;
        tmax[tid] = lenR[dir*NSEQ + t*CT];       // descending -> first rank in tile is max
    }
}

// -------- fused per-step kernel: compute blocks + gather blocks --------
// compute block = (ct, dir, mt): 16m x 3g x 32c; 4 waves = 4 K-splits of 200.
// thread-tile = 4m x 3g x 2c (24 acc). Barrier-free chunk loop (per-wave LDS).
__global__ __launch_bounds__(256)
void step_kernel(int s,
                 const float* __restrict__ actB_cur, float* __restrict__ actB_next,
                 float* __restrict__ c_final,
                 const float* __restrict__ WL, const float* __restrict__ UL, const float* __restrict__ bL,
                 const float* __restrict__ WR, const float* __restrict__ UR, const float* __restrict__ bR,
                 const int* __restrict__ perm, const int* __restrict__ lenR, const int* __restrict__ tmax,
                 const int* __restrict__ sup_tok, const int* __restrict__ tgt_tok,
                 const float* __restrict__ emb)
{
    const int bid = blockIdx.x;
    if (bid >= NCOMP) {
        // ---- gather x for step s+1 into actB_next rows k<300 ----
        const int gb = bid - NCOMP;
        const int d = gb / NSEQ;
        const int rank = gb % NSEQ;
        const int sn = s + 1;
        if (sn >= NSTEP) return;
        if (sn >= tmax[d*NCT + (rank >> 5)]) return;
        const int ch = perm[d*NSEQ + rank];
        const int tpos = d ? (T-1 - sn) : sn;
        const int tok = (ch < NSUP) ? sup_tok[ch*T + tpos] : tgt_tok[(ch-NSUP)*T + tpos];
        const float* src = emb + (size_t)tok*D;
        float* dst = actB_next + (size_t)d*KROW*NSEQ + rank;
        for (int k = threadIdx.x; k < D; k += 256) dst[(size_t)k*NSEQ] = src[k];
        return;
    }
    if (s < 0) return;
    // bid = ct*64 + d*32 + mt -> blocks sharing weight panel (d,mt) share bid%8 (XCD)
    const int ct = bid >> 6;
    const int dm = bid & 63;
    const int d  = dm >> 5;
    const int mt = dm & 31;
    if (s >= tmax[d*NCT + ct]) return;

    __shared__ float smem[SMSZ];

    const int tid  = threadIdx.x;
    const int ks   = tid >> 6;                   // wave = K split (k in [ks*200, ks*200+200))
    const int lane = tid & 63;
    const int ty   = lane >> 4;                  // 0..3: m-quad (m = mt*16 + ty*4 + j)
    const int tx   = lane & 15;                  // 0..15: chain pair
    const int rank0 = ct*CT;

    const float* Wd = d ? WR : WL;
    const float* Ud = d ? UR : UL;
    const float* bias = d ? bR : bL;

    float* As = smem + ks*APW;                   // [20 k][49]: g*16+ml
    float* Bs = smem + KSPL*APW + ks*BPW;        // [20 k][36]: chain

    // ---- hoisted per-lane staging geometry ----
    // A: 240 f4 slots = 48 rows x 5 kq;  slots lane, lane+64, lane+128, lane+192
    int aRow[4], aKq[4]; bool aVal[4];
    const float* aSrcW[4]; const float* aSrcU[4];
    float* aDst[4];
    #pragma unroll
    for (int i = 0; i < 4; ++i) {
        int slot = lane + 64*i;
        aVal[i] = (slot < 240);
        int row = aVal[i] ? slot/5 : 0;
        int kq  = aVal[i] ? slot%5 : 0;
        aRow[i] = row; aKq[i] = kq;
        int g = row >> 4, ml = row & 15;
        int m = mt*MT + ml; if (m >= M) m = M-1;           // clamp (harmless dup row)
        aSrcW[i] = Wd + (size_t)(g*M + m)*D + kq*4;
        aSrcU[i] = Ud + (size_t)(g*M + m)*M + kq*4;
        aDst[i]  = As + kq*4*ASTR + g*16 + ml;
    }
    // B: 160 f4 slots = 20 k x 8 quads; slots lane, lane+64, lane+128(<160)
    bool bVal[3]; const float* bSrc[3]; float* bDst[3];
    #pragma unroll
    for (int i = 0; i < 3; ++i) {
        int slot = lane + 64*i;
        bVal[i] = (slot < 160);
        int kk = (slot < 160 ? slot : 0) >> 3;
        int c4 = (slot < 160 ? slot : 0) & 7;
        bSrc[i] = actB_cur + ((size_t)d*KROW + kk)*NSEQ + rank0 + c4*4;
        bDst[i] = Bs + kk*BSTR + c4*4;
    }

    float4 aR4[4]; float4 bR4[3];
    auto loadA = [&](int gc){
        const int k0 = gc*CHK;
        const bool isx = (gc < 15);
        #pragma unroll
        for (int i = 0; i < 4; ++i)
            if (aVal[i]) aR4[i] = *(const float4*)(isx ? (aSrcW[i] + k0) : (aSrcU[i] + (k0-300)));
    };
    auto loadB = [&](int gc){
        const size_t ofs = (size_t)(gc*CHK)*NSEQ;
        #pragma unroll
        for (int i = 0; i < 3; ++i)
            if (bVal[i]) bR4[i] = *(const float4*)(bSrc[i] + ofs);
    };
    auto writeAB = [&](){
        #pragma unroll
        for (int i = 0; i < 4; ++i) {
            if (aVal[i]) {
                float* p = aDst[i];
                p[0*ASTR] = aR4[i].x; p[1*ASTR] = aR4[i].y;
                p[2*ASTR] = aR4[i].z; p[3*ASTR] = aR4[i].w;
            }
        }
        #pragma unroll
        for (int i = 0; i < 3; ++i)
            if (bVal[i]) *(float4*)bDst[i] = bR4[i];
    };

    float2 acc[4][3];
    #pragma unroll
    for (int j=0;j<4;++j)
        #pragma unroll
        for (int g=0;g<3;++g) acc[j][g] = make_float2(0.f,0.f);

    const float* Ard = As + ty*4;                // + k*ASTR + g*16  (imm)
    const float* Brd = Bs + tx*2;                // + k*BSTR         (imm)

    loadA(ks*CKS); loadB(ks*CKS);
    for (int ck = 0; ck < CKS; ++ck) {
        writeAB();
        if (ck + 1 < CKS) { loadA(ks*CKS + ck + 1); loadB(ks*CKS + ck + 1); }
        #pragma unroll
        for (int kk = 0; kk < CHK; ++kk) {
            float4 a0 = *(const float4*)(Ard + kk*ASTR);
            float4 a1 = *(const float4*)(Ard + kk*ASTR + 16);
            float4 a2 = *(const float4*)(Ard + kk*ASTR + 32);
            float2 b  = *(const float2*)(Brd + kk*BSTR);
            acc[0][0].x += a0.x*b.x; acc[0][0].y += a0.x*b.y;
            acc[1][0].x += a0.y*b.x; acc[1][0].y += a0.y*b.y;
            acc[2][0].x += a0.z*b.x; acc[2][0].y += a0.z*b.y;
            acc[3][0].x += a0.w*b.x; acc[3][0].y += a0.w*b.y;
            acc[0][1].x += a1.x*b.x; acc[0][1].y += a1.x*b.y;
            acc[1][1].x += a1.y*b.x; acc[1][1].y += a1.y*b.y;
            acc[2][1].x += a1.z*b.x; acc[2][1].y += a1.z*b.y;
            acc[3][1].x += a1.w*b.x; acc[3][1].y += a1.w*b.y;
            acc[0][2].x += a2.x*b.x; acc[0][2].y += a2.x*b.y;
            acc[1][2].x += a2.y*b.x; acc[1][2].y += a2.y*b.y;
            acc[2][2].x += a2.z*b.x; acc[2][2].y += a2.z*b.y;
            acc[3][2].x += a2.w*b.x; acc[3][2].y += a2.w*b.y;
        }
    }

    // ---- cross-split reduction through LDS (reuse smem: [ks][ml][3][32] = 6144) ----
    __syncthreads();
    float* red = smem;
    #pragma unroll
    for (int j=0;j<4;++j) {
        int ml = ty*4 + j;
        #pragma unroll
        for (int g=0;g<3;++g)
            *(float2*)&red[((ks*MT + ml)*3 + g)*CT + tx*2] = acc[j][g];
    }
    __syncthreads();

    // ---- final: sum splits + bias, gates, cell update (2 cells per thread) ----
    #pragma unroll
    for (int q=0;q<2;++q) {
        int cell = tid*2 + q;                    // 512 = 16 ml x 32 c
        int ml = cell >> 5, c = cell & 31;
        int m = mt*MT + ml;
        if (m < M) {
            float g0 = bias[m], g1 = bias[M + m], g2 = bias[2*M + m];
            #pragma unroll
            for (int kq=0;kq<KSPL;++kq) {
                g0 += red[((kq*MT + ml)*3 + 0)*CT + c];
                g1 += red[((kq*MT + ml)*3 + 1)*CT + c];
                g2 += red[((kq*MT + ml)*3 + 2)*CT + c];
            }
            int rank = rank0 + c;
            int len  = lenR[d*NSEQ + rank];
            size_t cidx = ((size_t)d*KROW + 300 + m)*NSEQ + rank;
            float cold = actB_cur[cidx];
            float f  = sigmoidf_(g0);
            float i2 = sigmoidf_(g1);
            float cb = tanhf(g2);
            float cn = (s < len) ? (f*cold + i2*cb) : cold;
            actB_next[cidx] = cn;
            if (s == len - 1) {
                int ch = perm[d*NSEQ + rank];
                c_final[((size_t)d*NSEQ + ch)*M + m] = cn;
            }
        }
    }
}

__global__ void env_kernel(const float* __restrict__ l_states, const float* __restrict__ r_states,
                           const float* __restrict__ Wo, const float* __restrict__ Uo,
                           const float* __restrict__ bo,
                           float* __restrict__ env)
{
    __shared__ __align__(16) float l[M];
    __shared__ __align__(16) float r[M];
    const int i = blockIdx.x;
    const int tid = threadIdx.x;
    for (int m=tid; m<M; m+=blockDim.x){ l[m]=l_states[i*M+m]; r[m]=r_states[i*M+m]; }
    __syncthreads();
    for (int d=tid; d<D; d+=blockDim.x) {
        const float4* wo = reinterpret_cast<const float4*>(Wo + (size_t)d*M);
        const float4* uo = reinterpret_cast<const float4*>(Uo + (size_t)d*M);
        const float4* lv = reinterpret_cast<const float4*>(l);
        const float4* rv = reinterpret_cast<const float4*>(r);
        float acc = bo[d];
        #pragma unroll 5
        for (int q=0; q<M/4; ++q) {
            float4 a=wo[q], bv=lv[q], u=uo[q], rr=rv[q];
            acc += a.x*bv.x + a.y*bv.y + a.z*bv.z + a.w*bv.w;
            acc += u.x*rr.x + u.y*rr.y + u.z*rr.z + u.w*rr.w;
        }
        env[i*D + d] = tanhf(acc);
    }
}

__global__ void episode_kernel(const float* __restrict__ env, const int* __restrict__ target_y,
                               float* __restrict__ flags, float* __restrict__ losses)
{
    const int b = blockIdx.x;
    const int lane = threadIdx.x;
    const float* tgt = env + (size_t)(NSUP + b)*D;

    float tn = 0.f;
    for (int d=lane; d<D; d+=64){ float v=tgt[d]; tn += v*v; }
    for (int off=32; off; off>>=1) tn += __shfl_down(tn, off);
    tn = __shfl(tn, 0);

    float z[NW];
    for (int n=0; n<NW; ++n){
        const float* sup = env + (size_t)(b*NW + n)*D;
        float dot=0.f, sn=0.f;
        for (int d=lane; d<D; d+=64){ float sv=sup[d], tv=tgt[d]; dot+=sv*tv; sn+=sv*sv; }
        for (int off=32; off; off>>=1){ dot += __shfl_down(dot,off); sn += __shfl_down(sn,off); }
        dot = __shfl(dot,0); sn = __shfl(sn,0);
        float denom = fmaxf(sqrtf(sn)*sqrtf(tn), 1e-8f);
        z[n] = dot/denom*10.0f;
    }

    if (lane==0){
        float mx=z[0];
        for(int n=1;n<NW;n++) mx=fmaxf(mx,z[n]);
        float se=0.f; float p[NW];
        for(int n=0;n<NW;n++){ p[n]=expf(z[n]-mx); se+=p[n]; }
        for(int n=0;n<NW;n++) p[n]/=se;
        int am=0; float bv=p[0];
        for(int n=1;n<NW;n++) if(p[n]>bv){bv=p[n];am=n;}
        int y = target_y[b];
        flags[b] = (am==y)?1.0f:0.0f;
        float mx2=p[0]; for(int n=1;n<NW;n++) mx2=fmaxf(mx2,p[n]);
        float se2=0.f; for(int n=0;n<NW;n++) se2+=expf(p[n]-mx2);
        losses[b] = -(p[y]-mx2-logf(se2));
    }
}

__global__ void finalize_kernel(const float* __restrict__ flags, const float* __restrict__ losses,
                                float* __restrict__ out)
{
    const int lane = threadIdx.x; // 64 threads
    float f = flags[lane], l = losses[lane];
    for (int off=32; off; off>>=1){ f += __shfl_down(f,off); l += __shfl_down(l,off); }
    if (lane==0){ out[0] = f/(float)B; out[1] = l/(float)B; }
}

extern "C" void kernel_launch(void* const* d_in, const int* in_sizes, int n_in,
                              void* d_out, int out_size, void* d_ws, size_t ws_size,
                              hipStream_t stream) {
    const int*   sup_tok   = (const int*)d_in[0];
    const int*   tgt_tok   = (const int*)d_in[1];
    const int*   blank_sup = (const int*)d_in[2];
    const int*   blank_tgt = (const int*)d_in[3];
    const int*   target_y  = (const int*)d_in[4];
    const float* emb = (const float*)d_in[5];
    const float* WL  = (const float*)d_in[6];
    const float* UL  = (const float*)d_in[7];
    const float* bL  = (const float*)d_in[8];
    const float* WR  = (const float*)d_in[9];
    const float* UR  = (const float*)d_in[10];
    const float* bR  = (const float*)d_in[11];
    const float* Wo  = (const float*)d_in[12];
    const float* Uo  = (const float*)d_in[13];
    const float* bo  = (const float*)d_in[14];
    const float* c0L = (const float*)d_in[15];
    const float* c0R = (const float*)d_in[16];

    const size_t ACTSZ = (size_t)2*KROW*NSEQ;           // 614400 floats
    float* ws_f = (float*)d_ws;
    float* actB0   = ws_f;
    float* actB1   = actB0 + ACTSZ;
    float* c_final = actB1 + ACTSZ;                     // [2*384*500]
    float* env     = c_final + 2*NSEQ*M;                // [384*300]
    float* flags   = env + NSEQ*D;                      // [64]
    float* losses  = flags + B;                         // [64]
    int*   perm    = (int*)(losses + B);                // [2*384]
    int*   lenR    = perm + 2*NSEQ;                     // [2*384]
    int*   tmax    = lenR + 2*NSEQ;                     // [24]

    init_kernel<<<(2*M*NSEQ + 255)/256, 256, 0, stream>>>(c0L, c0R, actB0, c_final);
    sort_kernel<<<1, NSEQ, 0, stream>>>(blank_sup, blank_tgt, perm, lenR, tmax);

    // prologue: gather x for step 0 into actB0 (compute blocks no-op at s=-1)
    step_kernel<<<NCOMP + NGATH, 256, 0, stream>>>(-1, actB1, actB0, c_final,
                                                   WL, UL, bL, WR, UR, bR,
                                                   perm, lenR, tmax, sup_tok, tgt_tok, emb);
    for (int s = 0; s < NSTEP; ++s) {
        float* cur  = (s & 1) ? actB1 : actB0;
        float* next = (s & 1) ? actB0 : actB1;
        step_kernel<<<NCOMP + NGATH, 256, 0, stream>>>(s, cur, next, c_final,
                                                       WL, UL, bL, WR, UR, bR,
                                                       perm, lenR, tmax, sup_tok, tgt_tok, emb);
    }

    env_kernel<<<NSEQ, 256, 0, stream>>>(c_final, c_final + NSEQ*M, Wo, Uo, bo, env);
    episode_kernel<<<B, 64, 0, stream>>>(env, target_y, flags, losses);
    finalize_kernel<<<1, 64, 0, stream>>>(flags, losses, (float*)d_out);
}

// Round 10
// 5088.216 us; speedup vs baseline: 2.9411x; 2.9411x over previous
//
#include <hip/hip_runtime.h>
#include <math.h>

#define V 13000
#define D 300
#define M 500
#define B 64
#define NW 5
#define T 128
#define NSUP (B*NW)        // 320
#define NSEQ (NSUP + B)    // 384
#define CT 32              // chains per compute tile
#define NCT 12             // 384/32
#define MT 16              // m per block
#define KSPL 4             // K splits (one wave each)
#define CHK 20             // k per chunk
#define CKS 10             // chunks per split (4*10*20 = 800)
#define KROW 800           // act row: k<300 = x, k>=300 = c(m=k-300)
#define NSTEP (T-1)        // 127
#define ASTR 68            // LDS floats per k-row of A (64 used + 4 pad)
#define BSTR 36            // LDS floats per k-row of B (32 used + 4 pad)
#define APW (CHK*ASTR)     // 1360 floats per split
#define BPW (CHK*BSTR)     // 720 floats per split
#define SMSZ (KSPL*(APW+BPW))  // 8320 floats = 33.3 KB
#define NCOMP 768          // 12 ct * 2 dir * 32 mt
#define NGATH 12           // 2 dir * 6 rank-tiles of 64

__device__ __forceinline__ float sigmoidf_(float x){ return 1.0f/(1.0f+expf(-x)); }

// actB layout: actB[(d*KROW + k)*NSEQ + rank]
// c_final layout: c_final[(d*NSEQ + chain)*M + m]

__global__ void init_kernel(const float* __restrict__ c0L, const float* __restrict__ c0R,
                            float* __restrict__ actB0, float* __restrict__ c_final)
{
    int idx = blockIdx.x*256 + threadIdx.x;      // 2*M*NSEQ
    if (idx >= 2*M*NSEQ) return;
    int d = idx / (M*NSEQ);
    int rem = idx % (M*NSEQ);
    int m = rem / NSEQ;
    int r = rem % NSEQ;
    float v = d ? c0R[m] : c0L[m];
    actB0[((size_t)d*KROW + 300 + m)*NSEQ + r] = v;
    c_final[((size_t)d*NSEQ + r)*M + m] = v;
}

__global__ void sort_kernel(const int* __restrict__ blank_sup, const int* __restrict__ blank_tgt,
                            int* __restrict__ perm, int* __restrict__ lenR, int* __restrict__ tmax)
{
    __shared__ int L0[NSEQ], L1[NSEQ];
    int tid = threadIdx.x;                       // 384 threads
    int blank = (tid < NSUP) ? blank_sup[tid] : blank_tgt[tid - NSUP];
    int l0 = blank, l1 = (T-1) - blank;
    L0[tid] = l0; L1[tid] = l1;
    __syncthreads();
    int r0 = 0, r1 = 0;
    for (int j = 0; j < NSEQ; ++j) {
        int c = L0[j]; r0 += (c > l0) || (c == l0 && j < tid);
        int d = L1[j]; r1 += (d > l1) || (d == l1 && j < tid);
    }
    perm[r0] = tid;        lenR[r0] = l0;
    perm[NSEQ + r1] = tid; lenR[NSEQ + r1] = l1;
    __syncthreads();
    if (tid < 2*NCT) {
        int dir = tid / NCT, t = tid % NCT;
        tmax[tid] = lenR[dir*NSEQ + t*CT];       // descending -> first rank in tile is max
    }
}

// -------- fused per-step kernel: 768 compute blocks + 12 gather blocks --------
__global__ __launch_bounds__(256)
void step_kernel(int s,
                 const float* __restrict__ actB_cur, float* __restrict__ actB_next,
                 float* __restrict__ c_final,
                 const float* __restrict__ WL, const float* __restrict__ UL, const float* __restrict__ bL,
                 const float* __restrict__ WR, const float* __restrict__ UR, const float* __restrict__ bR,
                 const int* __restrict__ perm, const int* __restrict__ lenR, const int* __restrict__ tmax,
                 const int* __restrict__ sup_tok, const int* __restrict__ tgt_tok,
                 const float* __restrict__ emb)
{
    const int bid = blockIdx.x;
    const int tid = threadIdx.x;

    if (bid >= NCOMP) {
        // ---- gather x for step s+1 into actB_next (coalesced: lane = rank) ----
        const int gb = bid - NCOMP;              // 0..11
        const int d  = gb / 6;
        const int rt = gb % 6;                   // 64-rank tile
        const int sn = s + 1;
        if (sn >= NSTEP) return;
        if (sn >= tmax[d*NCT + 2*rt]) return;    // both 32-tiles finished
        const int rr = tid & 63;                 // rank offset (coalesce axis)
        const int kk = tid >> 6;                 // 0..3
        const int rank = rt*64 + rr;
        const int ch = perm[d*NSEQ + rank];
        const int tpos = d ? (T-1 - sn) : sn;
        const int tok = (ch < NSUP) ? sup_tok[ch*T + tpos] : tgt_tok[(ch-NSUP)*T + tpos];
        const float* src = emb + (size_t)tok*D + kk;
        float* dst = actB_next + (size_t)d*KROW*NSEQ + rank;
        #pragma unroll 5
        for (int k4 = 0; k4 < 75; ++k4) {        // k = k4*4 + kk
            dst[(size_t)(k4*4 + kk)*NSEQ] = src[k4*4];
        }
        return;
    }
    if (s < 0) return;

    // bid = ct*64 + d*32 + mt -> blocks sharing weight panel (d,mt) share bid%8 (XCD)
    const int ct = bid >> 6;
    const int dm = bid & 63;
    const int d  = dm >> 5;
    const int mt = dm & 31;
    if (s >= tmax[d*NCT + ct]) return;

    __shared__ float smem[SMSZ];

    const int ks   = tid >> 6;                   // wave = K split
    const int lane = tid & 63;
    const int ty   = lane >> 3;                  // 0..7: m pair (ml = ty*2 + j)
    const int tx   = lane & 7;                   // 0..7: chain quad
    const int rank0 = ct*CT;

    const float* Wd = d ? WR : WL;
    const float* Ud = d ? UR : UL;
    const float* bias = d ? bR : bL;

    float* As = smem + ks*APW;                   // [20 k][68]: col = ml*4 + g
    float* Bs = smem + KSPL*APW + ks*BPW;        // [20 k][36]: col = chain

    // ---- hoisted staging geometry ----
    // A: 240 f4 slots = 48 rows x 5 kq; slots lane+64*i (i=0..2 always valid, i=3 if lane<48)
    const float* aW[4]; const float* aU[4]; float* aD[4];
    #pragma unroll
    for (int i = 0; i < 4; ++i) {
        int slot = lane + 64*i; if (slot >= 240) slot = 239;
        int row = slot/5, kq = slot%5;
        int g = row >> 4, ml = row & 15;
        int m = mt*MT + ml; if (m >= M) m = M-1;          // clamp (garbage discarded at write)
        aW[i] = Wd + (size_t)(g*M + m)*D + kq*4;
        aU[i] = Ud + (size_t)(g*M + m)*M + kq*4;
        aD[i] = As + kq*4*ASTR + ml*4 + g;
    }
    const bool a3 = (lane < 48);
    // B: 160 f4 slots = 20 k x 8 quads; slots lane+64*i (i=0,1 valid; i=2 if lane<32)
    const float* bS[3]; float* bD[3];
    #pragma unroll
    for (int i = 0; i < 3; ++i) {
        int slot = lane + 64*i; if (slot >= 160) slot = 159;
        int kk = slot >> 3, c4 = slot & 7;
        bS[i] = actB_cur + ((size_t)d*KROW + kk)*NSEQ + rank0 + c4*4;
        bD[i] = Bs + kk*BSTR + c4*4;
    }
    const bool b2 = (lane < 32);

    float4 aR4[4]; float4 bR4[3];
    auto loadA = [&](int gc){
        const int off = (gc < 15) ? gc*CHK : gc*CHK - 300;
        const bool isx = (gc < 15);
        aR4[0] = *(const float4*)((isx ? aW[0] : aU[0]) + off);
        aR4[1] = *(const float4*)((isx ? aW[1] : aU[1]) + off);
        aR4[2] = *(const float4*)((isx ? aW[2] : aU[2]) + off);
        if (a3) aR4[3] = *(const float4*)((isx ? aW[3] : aU[3]) + off);
    };
    auto loadB = [&](int gc){
        const size_t ofs = (size_t)(gc*CHK)*NSEQ;
        bR4[0] = *(const float4*)(bS[0] + ofs);
        bR4[1] = *(const float4*)(bS[1] + ofs);
        if (b2) bR4[2] = *(const float4*)(bS[2] + ofs);
    };
    auto writeAB = [&](){
        #pragma unroll
        for (int i = 0; i < 4; ++i) {
            if (i == 3 && !a3) break;
            float* p = aD[i];
            p[0] = aR4[i].x; p[ASTR] = aR4[i].y; p[2*ASTR] = aR4[i].z; p[3*ASTR] = aR4[i].w;
        }
        *(float4*)bD[0] = bR4[0];
        *(float4*)bD[1] = bR4[1];
        if (b2) *(float4*)bD[2] = bR4[2];
    };

    float4 acc[2][3];
    #pragma unroll
    for (int j=0;j<2;++j)
        #pragma unroll
        for (int g=0;g<3;++g) acc[j][g] = make_float4(0.f,0.f,0.f,0.f);

    const float* Ard = As + ty*8;                // + k*ASTR (+4 for second m)
    const float* Brd = Bs + tx*4;                // + k*BSTR

#define FMA4(AC, AV, BV) AC.x += (AV)*(BV).x; AC.y += (AV)*(BV).y; AC.z += (AV)*(BV).z; AC.w += (AV)*(BV).w;

    loadA(ks*CKS); loadB(ks*CKS);
    for (int ck = 0; ck < CKS; ++ck) {
        writeAB();
        if (ck + 1 < CKS) { loadA(ks*CKS + ck + 1); loadB(ks*CKS + ck + 1); }
        #pragma unroll
        for (int kk = 0; kk < CHK; ++kk) {
            float4 a0 = *(const float4*)(Ard + kk*ASTR);        // m=ty*2:   g0,g1,g2,pad
            float4 a1 = *(const float4*)(Ard + kk*ASTR + 4);    // m=ty*2+1
            float4 b  = *(const float4*)(Brd + kk*BSTR);
            FMA4(acc[0][0], a0.x, b);
            FMA4(acc[0][1], a0.y, b);
            FMA4(acc[0][2], a0.z, b);
            FMA4(acc[1][0], a1.x, b);
            FMA4(acc[1][1], a1.y, b);
            FMA4(acc[1][2], a1.z, b);
        }
    }
#undef FMA4

    // ---- cross-split reduction through LDS (reuse smem: [ks][ml 16][3][32] = 6144) ----
    __syncthreads();
    float* red = smem;
    #pragma unroll
    for (int j=0;j<2;++j) {
        int ml = ty*2 + j;
        #pragma unroll
        for (int g=0;g<3;++g)
            *(float4*)&red[((ks*MT + ml)*3 + g)*CT + tx*4] = acc[j][g];
    }
    __syncthreads();

    // ---- final: sum splits + bias, gates, cell update (2 cells per thread) ----
    #pragma unroll
    for (int q=0;q<2;++q) {
        int cell = tid*2 + q;                    // 512 = 16 ml x 32 c
        int ml = cell >> 5, c = cell & 31;
        int m = mt*MT + ml;
        if (m < M) {
            float g0 = bias[m], g1 = bias[M + m], g2 = bias[2*M + m];
            #pragma unroll
            for (int kq=0;kq<KSPL;++kq) {
                g0 += red[((kq*MT + ml)*3 + 0)*CT + c];
                g1 += red[((kq*MT + ml)*3 + 1)*CT + c];
                g2 += red[((kq*MT + ml)*3 + 2)*CT + c];
            }
            int rank = rank0 + c;
            int len  = lenR[d*NSEQ + rank];
            size_t cidx = ((size_t)d*KROW + 300 + m)*NSEQ + rank;
            float cold = actB_cur[cidx];
            float f  = sigmoidf_(g0);
            float i2 = sigmoidf_(g1);
            float cb = tanhf(g2);
            float cn = (s < len) ? (f*cold + i2*cb) : cold;
            actB_next[cidx] = cn;
            if (s == len - 1) {
                int ch = perm[d*NSEQ + rank];
                c_final[((size_t)d*NSEQ + ch)*M + m] = cn;
            }
        }
    }
}

__global__ void env_kernel(const float* __restrict__ l_states, const float* __restrict__ r_states,
                           const float* __restrict__ Wo, const float* __restrict__ Uo,
                           const float* __restrict__ bo,
                           float* __restrict__ env)
{
    __shared__ __align__(16) float l[M];
    __shared__ __align__(16) float r[M];
    const int i = blockIdx.x;
    const int tid = threadIdx.x;
    for (int m=tid; m<M; m+=blockDim.x){ l[m]=l_states[i*M+m]; r[m]=r_states[i*M+m]; }
    __syncthreads();
    for (int d=tid; d<D; d+=blockDim.x) {
        const float4* wo = reinterpret_cast<const float4*>(Wo + (size_t)d*M);
        const float4* uo = reinterpret_cast<const float4*>(Uo + (size_t)d*M);
        const float4* lv = reinterpret_cast<const float4*>(l);
        const float4* rv = reinterpret_cast<const float4*>(r);
        float acc = bo[d];
        #pragma unroll 5
        for (int q=0; q<M/4; ++q) {
            float4 a=wo[q], bv=lv[q], u=uo[q], rr=rv[q];
            acc += a.x*bv.x + a.y*bv.y + a.z*bv.z + a.w*bv.w;
            acc += u.x*rr.x + u.y*rr.y + u.z*rr.z + u.w*rr.w;
        }
        env[i*D + d] = tanhf(acc);
    }
}

__global__ void episode_kernel(const float* __restrict__ env, const int* __restrict__ target_y,
                               float* __restrict__ flags, float* __restrict__ losses)
{
    const int b = blockIdx.x;
    const int lane = threadIdx.x;
    const float* tgt = env + (size_t)(NSUP + b)*D;

    float tn = 0.f;
    for (int d=lane; d<D; d+=64){ float v=tgt[d]; tn += v*v; }
    for (int off=32; off; off>>=1) tn += __shfl_down(tn, off);
    tn = __shfl(tn, 0);

    float z[NW];
    for (int n=0; n<NW; ++n){
        const float* sup = env + (size_t)(b*NW + n)*D;
        float dot=0.f, sn=0.f;
        for (int d=lane; d<D; d+=64){ float sv=sup[d], tv=tgt[d]; dot+=sv*tv; sn+=sv*sv; }
        for (int off=32; off; off>>=1){ dot += __shfl_down(dot,off); sn += __shfl_down(sn,off); }
        dot = __shfl(dot,0); sn = __shfl(sn,0);
        float denom = fmaxf(sqrtf(sn)*sqrtf(tn), 1e-8f);
        z[n] = dot/denom*10.0f;
    }

    if (lane==0){
        float mx=z[0];
        for(int n=1;n<NW;n++) mx=fmaxf(mx,z[n]);
        float se=0.f; float p[NW];
        for(int n=0;n<NW;n++){ p[n]=expf(z[n]-mx); se+=p[n]; }
        for(int n=0;n<NW;n++) p[n]/=se;
        int am=0; float bv=p[0];
        for(int n=1;n<NW;n++) if(p[n]>bv){bv=p[n];am=n;}
        int y = target_y[b];
        flags[b] = (am==y)?1.0f:0.0f;
        float mx2=p[0]; for(int n=1;n<NW;n++) mx2=fmaxf(mx2,p[n]);
        float se2=0.f; for(int n=0;n<NW;n++) se2+=expf(p[n]-mx2);
        losses[b] = -(p[y]-mx2-logf(se2));
    }
}

__global__ void finalize_kernel(const float* __restrict__ flags, const float* __restrict__ losses,
                                float* __restrict__ out)
{
    const int lane = threadIdx.x; // 64 threads
    float f = flags[lane], l = losses[lane];
    for (int off=32; off; off>>=1){ f += __shfl_down(f,off); l += __shfl_down(l,off); }
    if (lane==0){ out[0] = f/(float)B; out[1] = l/(float)B; }
}

extern "C" void kernel_launch(void* const* d_in, const int* in_sizes, int n_in,
                              void* d_out, int out_size, void* d_ws, size_t ws_size,
                              hipStream_t stream) {
    const int*   sup_tok   = (const int*)d_in[0];
    const int*   tgt_tok   = (const int*)d_in[1];
    const int*   blank_sup = (const int*)d_in[2];
    const int*   blank_tgt = (const int*)d_in[3];
    const int*   target_y  = (const int*)d_in[4];
    const float* emb = (const float*)d_in[5];
    const float* WL  = (const float*)d_in[6];
    const float* UL  = (const float*)d_in[7];
    const float* bL  = (const float*)d_in[8];
    const float* WR  = (const float*)d_in[9];
    const float* UR  = (const float*)d_in[10];
    const float* bR  = (const float*)d_in[11];
    const float* Wo  = (const float*)d_in[12];
    const float* Uo  = (const float*)d_in[13];
    const float* bo  = (const float*)d_in[14];
    const float* c0L = (const float*)d_in[15];
    const float* c0R = (const float*)d_in[16];

    const size_t ACTSZ = (size_t)2*KROW*NSEQ;           // 614400 floats
    float* ws_f = (float*)d_ws;
    float* actB0   = ws_f;
    float* actB1   = actB0 + ACTSZ;
    float* c_final = actB1 + ACTSZ;                     // [2*384*500]
    float* env     = c_final + 2*NSEQ*M;                // [384*300]
    float* flags   = env + NSEQ*D;                      // [64]
    float* losses  = flags + B;                         // [64]
    int*   perm    = (int*)(losses + B);                // [2*384]
    int*   lenR    = perm + 2*NSEQ;                     // [2*384]
    int*   tmax    = lenR + 2*NSEQ;                     // [24]

    init_kernel<<<(2*M*NSEQ + 255)/256, 256, 0, stream>>>(c0L, c0R, actB0, c_final);
    sort_kernel<<<1, NSEQ, 0, stream>>>(blank_sup, blank_tgt, perm, lenR, tmax);

    // prologue: gather x for step 0 into actB0 (compute blocks no-op at s=-1)
    step_kernel<<<NCOMP + NGATH, 256, 0, stream>>>(-1, actB1, actB0, c_final,
                                                   WL, UL, bL, WR, UR, bR,
                                                   perm, lenR, tmax, sup_tok, tgt_tok, emb);
    for (int s = 0; s < NSTEP; ++s) {
        float* cur  = (s & 1) ? actB1 : actB0;
        float* next = (s & 1) ? actB0 : actB1;
        step_kernel<<<NCOMP + NGATH, 256, 0, stream>>>(s, cur, next, c_final,
                                                       WL, UL, bL, WR, UR, bR,
                                                       perm, lenR, tmax, sup_tok, tgt_tok, emb);
    }

    env_kernel<<<NSEQ, 256, 0, stream>>>(c_final, c_final + NSEQ*M, Wo, Uo, bo, env);
    episode_kernel<<<B, 64, 0, stream>>>(env, target_y, flags, losses);
    finalize_kernel<<<1, 64, 0, stream>>>(flags, losses, (float*)d_out);
}